// Round 12
// baseline (409.117 us; speedup 1.0000x reference)
//
#include <hip/hip_runtime.h>
#include <hip/hip_fp16.h>

#define HC 128
#define EPS_BN 1e-5f
#define NSTRIPE 8
#define AGG_BLOCKS 3072          // multiple of 8
#define BSHIFT 9                 // 512 nodes per bucket
#define BNODES (1 << BSHIFT)
#define CHUNK 8192               // edges per pass-1 block
#define SRC_BITS 18              // src < 2^18

typedef _Float16 f16;
typedef f16  f16x8 __attribute__((ext_vector_type(8)));
typedef float f32x4 __attribute__((ext_vector_type(4)));

// ---------------- A1: per-bucket histogram (1024 thr for TLP) ---------------
__global__ __launch_bounds__(1024) void bucket_count(const int* __restrict__ dst,
                                                     int* __restrict__ bcnt, int E) {
    __shared__ int c[256];
    const int tid = threadIdx.x;
    const int e0 = blockIdx.x * CHUNK;
    if (tid < 256) c[tid] = 0;
    __syncthreads();
    for (int i = tid; i < CHUNK; i += 1024) {
        int e = e0 + i;
        if (e < E) atomicAdd(&c[dst[e] >> BSHIFT], 1);
    }
    __syncthreads();
    if (tid < 256 && c[tid] > 0) atomicAdd(&bcnt[tid], c[tid]);
}

// ---------------- A2: scan buckets -> bbase, gcur; rowptr[n]=E --------------
__global__ __launch_bounds__(256) void bscan(const int* __restrict__ bcnt,
                                             int* __restrict__ bbase, int* __restrict__ gcur,
                                             int* __restrict__ rowptr, int nb, int n, int E) {
    __shared__ int s[256];
    const int tid = threadIdx.x;
    s[tid] = (tid < nb) ? bcnt[tid] : 0;
    __syncthreads();
    for (int off = 1; off < 256; off <<= 1) {
        int t = (tid >= off) ? s[tid - off] : 0;
        __syncthreads();
        s[tid] += t;
        __syncthreads();
    }
    int excl = tid ? s[tid - 1] : 0;
    if (tid < nb) { bbase[tid] = excl; gcur[tid] = excl; }
    if (tid == 0) { bbase[nb] = E; rowptr[n] = E; }
}

// ---------------- pass 1: block-private bucket runs (1024 thr) --------------
__global__ __launch_bounds__(1024) void edge_bin(const int* __restrict__ src,
                                                 const int* __restrict__ dst,
                                                 int* __restrict__ gcur,
                                                 unsigned int* __restrict__ packed, int E) {
    __shared__ int cnt[256];
    __shared__ int cur[256];
    const int tid = threadIdx.x;
    const int e0 = blockIdx.x * CHUNK;
    if (tid < 256) cnt[tid] = 0;
    __syncthreads();
    for (int i = tid; i < CHUNK; i += 1024) {
        int e = e0 + i;
        if (e < E) atomicAdd(&cnt[dst[e] >> BSHIFT], 1);
    }
    __syncthreads();
    if (tid < 256) cur[tid] = (cnt[tid] > 0) ? atomicAdd(&gcur[tid], cnt[tid]) : 0;
    __syncthreads();
    for (int i = tid; i < CHUNK; i += 1024) {
        int e = e0 + i;
        if (e < E) {
            int s = src[e], d = dst[e];
            int pos = atomicAdd(&cur[d >> BSHIFT], 1);
            packed[pos] = ((unsigned)(d & (BNODES - 1)) << SRC_BITS) | (unsigned)s;
        }
    }
}

// ---------------- pass 2: per-bucket degree+scan+placement (1024 thr) -------
__global__ __launch_bounds__(1024) void edge_sort(const unsigned int* __restrict__ packed,
                                                  const int* __restrict__ bbase,
                                                  int* __restrict__ rowptr,
                                                  float* __restrict__ dis,
                                                  int* __restrict__ srcs, int n) {
    __shared__ int cnt[BNODES];
    __shared__ int cur[BNODES];
    __shared__ int scn[BNODES];
    const int b = blockIdx.x;
    const int node0 = b << BSHIFT;
    const int tid = threadIdx.x;
    const int base = bbase[b];
    const int end  = bbase[b + 1];

    if (tid < BNODES) cnt[tid] = 0;
    __syncthreads();
    for (int e = base + tid; e < end; e += 1024)
        atomicAdd(&cnt[packed[e] >> SRC_BITS], 1);
    __syncthreads();
    if (tid < BNODES) scn[tid] = cnt[tid];
    __syncthreads();
    for (int off = 1; off < BNODES; off <<= 1) {
        int t = 0;
        if (tid < BNODES && tid >= off) t = scn[tid - off];
        __syncthreads();
        if (tid < BNODES) scn[tid] += t;
        __syncthreads();
    }
    if (tid < BNODES) {
        int excl = scn[tid] - cnt[tid];
        int node = node0 + tid;
        if (node < n) {
            rowptr[node] = base + excl;
            dis[node] = rsqrtf((float)cnt[tid] + 1.f);
        }
        cur[tid] = excl;
    }
    __syncthreads();
    for (int e = base + tid; e < end; e += 1024) {
        unsigned p = packed[e];
        int pos = atomicAdd(&cur[p >> SRC_BITS], 1);
        srcs[base + pos] = (int)(p & ((1u << SRC_BITS) - 1));
    }
}

// ---------------- weight prep (all) + zero pad rows of sliced xws -----------
__global__ void wprep_all(const float* __restrict__ W1, const float* __restrict__ W2,
                          const float* __restrict__ Wm1,
                          f16* __restrict__ Wt1, f16* __restrict__ Wt2,
                          f16* __restrict__ Wm1t, f16* __restrict__ xws,
                          int n, int sstride16) {
    int idx = blockIdx.x * 256 + threadIdx.x;
    if (idx < 16384) {
        int k = idx >> 7, c = idx & 127;
        Wt1[(size_t)c * HC + k] = (f16)W1[idx];
    } else if (idx < 32768) {
        int i = idx - 16384;
        int k = i >> 7, c = i & 127;
        Wt2[(size_t)c * HC + k] = (f16)W2[i];
    } else if (idx < 40960) {
        int i = idx - 32768;
        int c = i >> 7, k = i & 127;
        Wm1t[(size_t)c * HC + k] = (f16)Wm1[(size_t)k * 64 + c];
    } else if (idx < 41088) {
        int i = idx - 40960;                       // 128 pad entries: 8 slices x 16
        int slice = i >> 4, j = i & 15;
        xws[(size_t)slice * sstride16 + (size_t)n * 16 + j] = (f16)0.f;
    }
}

// ---------------- MFMA GEMM: Y_sl[t][row][16] = dis[row]*(T(X)[row] @ W) ----
// Output in slice-major layout: Y + t*sstride16 + row*16 + m.
template<int SRC_F16, int TRANS>
__global__ __launch_bounds__(256) void gemm_mfma(const void* __restrict__ Xv,
                                                 const f16* __restrict__ Wt,
                                                 const float* __restrict__ stats,
                                                 const float* __restrict__ gamma,
                                                 const float* __restrict__ beta,
                                                 const float* __restrict__ dis,
                                                 f16* __restrict__ Y, int n, int sstride16) {
    __shared__ f16 Ah[64][136];
    __shared__ f16 Bh[128][136];
    __shared__ float sc[HC], sh[HC];
    const int tid  = threadIdx.x;
    const int row0 = blockIdx.x * 64;

    if constexpr (TRANS) {
        if (tid < 128) {
            float s = 0.f, q = 0.f;
#pragma unroll
            for (int t = 0; t < NSTRIPE; ++t) {
                s += stats[t * 256 + tid];
                q += stats[t * 256 + 128 + tid];
            }
            float m = s / (float)n;
            float v = q / (float)n - m * m;
            float scv = gamma[tid] * rsqrtf(fmaxf(v, 0.f) + EPS_BN);
            sc[tid] = scv;
            sh[tid] = beta[tid] - m * scv;
        }
    }

#pragma unroll
    for (int i = 0; i < 8; ++i) {
        int idx = i * 256 + tid;
        int r = idx >> 4, g = idx & 15;
        *(f16x8*)&Bh[r][g * 8] = *(const f16x8*)(Wt + (size_t)r * HC + g * 8);
    }
    __syncthreads();

#pragma unroll
    for (int i = 0; i < 4; ++i) {
        int idx = i * 256 + tid;
        int r = idx >> 4, g = idx & 15;
        int grow = row0 + r;
        f16x8 h = {};
        if (grow < n) {
            if constexpr (SRC_F16) {
                f16x8 v = *(const f16x8*)((const f16*)Xv + (size_t)grow * HC + g * 8);
                if constexpr (TRANS) {
#pragma unroll
                    for (int j = 0; j < 8; ++j) {
                        float f = (float)v[j];
                        f = fmaxf(fmaf(f, sc[g * 8 + j], sh[g * 8 + j]), 0.f);
                        h[j] = (f16)f;
                    }
                } else h = v;
            } else {
                const float* X = (const float*)Xv;
                float4 a = *(const float4*)(X + (size_t)grow * HC + g * 8);
                float4 c = *(const float4*)(X + (size_t)grow * HC + g * 8 + 4);
                h[0] = (f16)a.x; h[1] = (f16)a.y; h[2] = (f16)a.z; h[3] = (f16)a.w;
                h[4] = (f16)c.x; h[5] = (f16)c.y; h[6] = (f16)c.z; h[7] = (f16)c.w;
            }
        }
        *(f16x8*)&Ah[r][g * 8] = h;
    }
    __syncthreads();

    const int wv   = tid >> 6;
    const int lane = tid & 63;
    const int m    = lane & 15;
    const int kq   = (lane >> 4) * 8;

    f32x4 acc[8] = {};
#pragma unroll
    for (int kc = 0; kc < HC; kc += 32) {
        f16x8 a = *(const f16x8*)&Ah[wv * 16 + m][kc + kq];
#pragma unroll
        for (int t = 0; t < 8; ++t) {
            f16x8 b = *(const f16x8*)&Bh[t * 16 + m][kc + kq];
            acc[t] = __builtin_amdgcn_mfma_f32_16x16x32_f16(a, b, acc[t], 0, 0, 0);
        }
    }

    const int rbase = row0 + wv * 16 + (lane >> 4) * 4;
#pragma unroll
    for (int r = 0; r < 4; ++r) {
        int grow = rbase + r;
        if (grow < n) {
            float dv = dis[grow];
#pragma unroll
            for (int t = 0; t < 8; ++t)
                Y[(size_t)t * sstride16 + (size_t)grow * 16 + m] = (f16)(acc[t][r] * dv);
        }
    }
}

// ---------------- sliced CSR gather agg (XCD-pinned channel slices) ---------
// Block handles slice = blockIdx&7 (16 ch, 3.2 MB region -> L2-resident).
// Wave: 4 nodes x 8 edge-slots x 2 ch-halves; out row-major; fused BN stats.
__global__ __launch_bounds__(256) void gcn_agg_sl(const f16* __restrict__ xws,
                                                  const int* __restrict__ srcs,
                                                  const int* __restrict__ rowptr,
                                                  const float* __restrict__ dis,
                                                  const float* __restrict__ bias,
                                                  f16* __restrict__ out,
                                                  float* __restrict__ stats,
                                                  int n, int sstride16) {
    __shared__ float lds_s[4][4][2][8], lds_q[4][4][2][8];
    const int tid   = threadIdx.x;
    const int wv    = tid >> 6;
    const int lane  = tid & 63;
    const int npos  = lane >> 4;        // node within quad
    const int ei    = (lane >> 1) & 7;  // edge slot
    const int h     = lane & 1;         // channel half (8 ch)
    const int slice = blockIdx.x & 7;
    const int blkSl = blockIdx.x >> 3;  // block index within slice
    const int nodeStride = (AGG_BLOCKS >> 3) * 16;   // waves/slice * 4 nodes

    const f16* xsl = xws + (size_t)slice * sstride16;

    float b8[8];
#pragma unroll
    for (int j = 0; j < 8; ++j) b8[j] = bias[slice * 16 + h * 8 + j];

    float s8[8] = {}, q8[8] = {};

    for (int nb = (blkSl * 4 + wv) * 4 + npos; nb < n; nb += nodeStride) {
        const int e0 = rowptr[nb];
        const int e1 = rowptr[nb + 1];
        float acc[8] = {};
        for (int e = e0; e < e1; e += 8) {
            int idx = e + ei;
            int s = (idx < e1) ? srcs[idx] : n;
            f16x8 v = *(const f16x8*)(xsl + (size_t)s * 16 + h * 8);
#pragma unroll
            for (int j = 0; j < 8; ++j) acc[j] += (float)v[j];
        }
        // reduce across 8 edge slots (lane bits 1..3)
#pragma unroll
        for (int j = 0; j < 8; ++j) acc[j] += __shfl_xor(acc[j], 2);
#pragma unroll
        for (int j = 0; j < 8; ++j) acc[j] += __shfl_xor(acc[j], 4);
#pragma unroll
        for (int j = 0; j < 8; ++j) acc[j] += __shfl_xor(acc[j], 8);

        if (ei == 0) {
            float dv = dis[nb];
            f16x8 self = *(const f16x8*)(xsl + (size_t)nb * 16 + h * 8);
            f16x8 o;
#pragma unroll
            for (int j = 0; j < 8; ++j) {
                float r = fmaf(acc[j] + (float)self[j], dv, b8[j]);
                o[j] = (f16)r;
                s8[j] += r;
                q8[j] += r * r;
            }
            *(f16x8*)(out + (size_t)nb * HC + slice * 16 + h * 8) = o;
        }
    }

    if (ei == 0) {
#pragma unroll
        for (int j = 0; j < 8; ++j) {
            lds_s[wv][npos][h][j] = s8[j];
            lds_q[wv][npos][h][j] = q8[j];
        }
    }
    __syncthreads();
    if (tid < 16) {
        int hh = tid >> 3, j = tid & 7;
        float s = 0.f, q = 0.f;
#pragma unroll
        for (int w = 0; w < 4; ++w)
#pragma unroll
            for (int p = 0; p < 4; ++p) {
                s += lds_s[w][p][hh][j];
                q += lds_q[w][p][hh][j];
            }
        int ch = slice * 16 + hh * 8 + j;
        float* stripe = stats + (size_t)((blockIdx.x >> 3) & (NSTRIPE - 1)) * 256;
        atomicAdd(&stripe[ch], s);
        atomicAdd(&stripe[128 + ch], q);
    }
}

// ---------------- MFMA MLP head (BN2 finalize + BN+ReLU + both layers) ------
__global__ __launch_bounds__(256) void mlp_mfma(const f16* __restrict__ h,
                                                const float* __restrict__ stats,
                                                const float* __restrict__ gamma,
                                                const float* __restrict__ beta,
                                                const f16* __restrict__ Wm1t,
                                                const float* __restrict__ bm1,
                                                const float* __restrict__ Wm2,
                                                const float* __restrict__ bm2,
                                                float* __restrict__ out, int n) {
    __shared__ f16 Hs[64][136];
    __shared__ f16 Ws[64][136];
    __shared__ float sc[HC], sh[HC], bmv[64], w2v[64];
    const int tid  = threadIdx.x;
    const int row0 = blockIdx.x * 64;

    if (tid < 128) {
        float s = 0.f, q = 0.f;
#pragma unroll
        for (int t = 0; t < NSTRIPE; ++t) {
            s += stats[t * 256 + tid];
            q += stats[t * 256 + 128 + tid];
        }
        float m = s / (float)n;
        float v = q / (float)n - m * m;
        float scv = gamma[tid] * rsqrtf(fmaxf(v, 0.f) + EPS_BN);
        sc[tid] = scv;
        sh[tid] = beta[tid] - m * scv;
    }
    if (tid < 64) { bmv[tid] = bm1[tid]; w2v[tid] = Wm2[tid]; }

#pragma unroll
    for (int i = 0; i < 4; ++i) {
        int idx = i * 256 + tid;
        int r = idx >> 4, g = idx & 15;
        *(f16x8*)&Ws[r][g * 8] = *(const f16x8*)(Wm1t + (size_t)r * HC + g * 8);
    }
    __syncthreads();

#pragma unroll
    for (int i = 0; i < 4; ++i) {
        int idx = i * 256 + tid;
        int r = idx >> 4, g = idx & 15;
        int grow = row0 + r;
        f16x8 hv = {};
        if (grow < n) {
            f16x8 v = *(const f16x8*)(h + (size_t)grow * HC + g * 8);
#pragma unroll
            for (int j = 0; j < 8; ++j) {
                float f = (float)v[j];
                f = fmaxf(fmaf(f, sc[g * 8 + j], sh[g * 8 + j]), 0.f);
                hv[j] = (f16)f;
            }
        }
        *(f16x8*)&Hs[r][g * 8] = hv;
    }
    __syncthreads();

    const int wv   = tid >> 6;
    const int lane = tid & 63;
    const int m    = lane & 15;
    const int kq   = (lane >> 4) * 8;

    f32x4 acc[4] = {};
#pragma unroll
    for (int kc = 0; kc < HC; kc += 32) {
        f16x8 a = *(const f16x8*)&Hs[wv * 16 + m][kc + kq];
#pragma unroll
        for (int t = 0; t < 4; ++t) {
            f16x8 b = *(const f16x8*)&Ws[t * 16 + m][kc + kq];
            acc[t] = __builtin_amdgcn_mfma_f32_16x16x32_f16(a, b, acc[t], 0, 0, 0);
        }
    }

    float part[4];
#pragma unroll
    for (int reg = 0; reg < 4; ++reg) {
        float s = 0.f;
#pragma unroll
        for (int t = 0; t < 4; ++t) {
            int col = t * 16 + m;
            s += fmaxf(acc[t][reg] + bmv[col], 0.f) * w2v[col];
        }
        part[reg] = s;
    }
#pragma unroll
    for (int off = 1; off < 16; off <<= 1) {
#pragma unroll
        for (int reg = 0; reg < 4; ++reg)
            part[reg] += __shfl_xor(part[reg], off);
    }
    if (m == 0) {
        int rbase = row0 + wv * 16 + (lane >> 4) * 4;
        float bb = bm2[0];
#pragma unroll
        for (int reg = 0; reg < 4; ++reg) {
            int row = rbase + reg;
            if (row < n) out[row] = part[reg] + bb;
        }
    }
}

extern "C" void kernel_launch(void* const* d_in, const int* in_sizes, int n_in,
                              void* d_out, int out_size, void* d_ws, size_t ws_size,
                              hipStream_t stream) {
    const float* x   = (const float*)d_in[0];
    const int*   ei  = (const int*)  d_in[1];
    const float* W1  = (const float*)d_in[2];
    const float* b1  = (const float*)d_in[3];
    const float* g1  = (const float*)d_in[4];
    const float* be1 = (const float*)d_in[5];
    const float* W2  = (const float*)d_in[6];
    const float* b2  = (const float*)d_in[7];
    const float* g2  = (const float*)d_in[8];
    const float* be2 = (const float*)d_in[9];
    const float* Wm1 = (const float*)d_in[10];
    const float* bm1 = (const float*)d_in[11];
    const float* Wm2 = (const float*)d_in[12];
    const float* bm2 = (const float*)d_in[13];
    float* out = (float*)d_out;

    const int n = in_sizes[0] / HC;       // 100000
    const int E = in_sizes[1] / 2;        // 1600000
    const int* srcp = ei;
    const int* dstp = ei + E;
    const int nb = (n + BNODES - 1) >> BSHIFT;   // 196 buckets
    const int sstride16 = (n + 1) * 16;          // slice stride in halves

    char* ws = (char*)d_ws;
    size_t off = 0;
    auto alloc = [&](size_t bytes) { void* p = ws + off; off = (off + bytes + 511) & ~511ULL; return p; };
    float*  dis    = (float*) alloc((size_t)n * 4);
    int*    rowptr = (int*)   alloc((size_t)(n + 1) * 4);
    // contiguous zero region: bcnt(256) | stats1(2048) | stats2(2048) floats
    int*    zreg   = (int*)   alloc((256 + 2 * NSTRIPE * 256) * 4);
    int*    bcnt   = zreg;
    float*  stats1 = (float*)(zreg + 256);
    float*  stats2 = stats1 + NSTRIPE * 256;
    int*    bbase  = (int*)   alloc(1024 + 4);
    int*    gcur   = (int*)   alloc(1024);
    unsigned int* packed = (unsigned int*)alloc((size_t)E * 4);
    int*    srcs   = (int*)   alloc((size_t)E * 4);
    f16*    xws    = (f16*)   alloc((size_t)8 * sstride16 * 2);  // sliced, +pad row per slice
    f16*    bufBh  = (f16*)   alloc((size_t)n * HC * 2);
    f16*    Wt1    = (f16*)   alloc((size_t)HC * HC * 2);
    f16*    Wt2    = (f16*)   alloc((size_t)HC * HC * 2);
    f16*    Wm1t   = (f16*)   alloc((size_t)64 * HC * 2);

    const int gemmBlocks = (n + 63) / 64;
    const int binBlocks  = (E + CHUNK - 1) / CHUNK;

    // ---- single fused zero init ----
    hipMemsetAsync(zreg, 0, (256 + 2 * NSTRIPE * 256) * 4, stream);

    // ---- CSR build: bucket histogram -> scan -> bin -> per-bucket sort ----
    bucket_count<<<binBlocks, 1024, 0, stream>>>(dstp, bcnt, E);
    bscan<<<1, 256, 0, stream>>>(bcnt, bbase, gcur, rowptr, nb, n, E);
    edge_bin<<<binBlocks, 1024, 0, stream>>>(srcp, dstp, gcur, packed, E);
    edge_sort<<<nb, 1024, 0, stream>>>(packed, bbase, rowptr, dis, srcs, n);

    // ---- weight prep + pad-row zero ----
    wprep_all<<<(41088 + 255) / 256, 256, 0, stream>>>(W1, W2, Wm1, Wt1, Wt2, Wm1t,
                                                       xws, n, sstride16);

    // ---- layer 1 ----
    gemm_mfma<0, 0><<<gemmBlocks, 256, 0, stream>>>(x, Wt1, nullptr, nullptr, nullptr,
                                                    dis, xws, n, sstride16);
    gcn_agg_sl<<<AGG_BLOCKS, 256, 0, stream>>>(xws, srcs, rowptr, dis, b1,
                                               bufBh, stats1, n, sstride16);

    // ---- layer 2 (BN1 finalize + BN+ReLU fused into GEMM staging) ----
    gemm_mfma<1, 1><<<gemmBlocks, 256, 0, stream>>>(bufBh, Wt2, stats1, g1, be1,
                                                    dis, xws, n, sstride16);
    gcn_agg_sl<<<AGG_BLOCKS, 256, 0, stream>>>(xws, srcs, rowptr, dis, b2,
                                               bufBh, stats2, n, sstride16);

    // ---- MLP head (BN2 finalize + BN+ReLU + both layers fused, MFMA) ----
    mlp_mfma<<<gemmBlocks, 256, 0, stream>>>(bufBh, stats2, g2, be2, Wm1t, bm1, Wm2, bm2,
                                             out, n);
}

// Round 13
// 318.745 us; speedup vs baseline: 1.2835x; 1.2835x over previous
//
#include <hip/hip_runtime.h>
#include <hip/hip_fp16.h>

#define HC 128
#define EPS_BN 1e-5f
#define NSTRIPE 8
#define AGG_BLOCKS 3072
#define BSHIFT 9                 // 512 nodes per bucket
#define BNODES (1 << BSHIFT)
#define BCAP 12288               // bucket capacity (mean 8192 + 45 sigma)
#define CHUNK 8192               // edges per pass-1 block
#define SRC_BITS 18              // src < 2^18

typedef _Float16 f16;
typedef f16  f16x8 __attribute__((ext_vector_type(8)));
typedef float f32x4 __attribute__((ext_vector_type(4)));

// ---------------- prologue: weight prep + pad row + gcur init + stats zero --
__global__ void prologue(const float* __restrict__ W1, const float* __restrict__ W2,
                         const float* __restrict__ Wm1,
                         f16* __restrict__ Wt1, f16* __restrict__ Wt2,
                         f16* __restrict__ Wm1t, f16* __restrict__ padrow,
                         int* __restrict__ gcur, float* __restrict__ stats) {
    int idx = blockIdx.x * 256 + threadIdx.x;
    if (idx < 16384) {
        int k = idx >> 7, c = idx & 127;
        Wt1[(size_t)c * HC + k] = (f16)W1[idx];
    } else if (idx < 32768) {
        int i = idx - 16384;
        int k = i >> 7, c = i & 127;
        Wt2[(size_t)c * HC + k] = (f16)W2[i];
    } else if (idx < 40960) {
        int i = idx - 32768;
        int c = i >> 7, k = i & 127;
        Wm1t[(size_t)c * HC + k] = (f16)Wm1[(size_t)k * 64 + c];
    } else if (idx < 41088) {
        padrow[idx - 40960] = (f16)0.f;
    } else if (idx < 41344) {
        int b = idx - 41088;
        gcur[b] = b * BCAP;
    } else if (idx < 45440) {
        stats[idx - 41344] = 0.f;
    }
}

// ---------------- pass 1: block-private runs into fixed bucket regions ------
__global__ __launch_bounds__(1024) void edge_bin(const int* __restrict__ src,
                                                 const int* __restrict__ dst,
                                                 int* __restrict__ gcur,
                                                 unsigned int* __restrict__ packed, int E) {
    __shared__ int cnt[256];
    __shared__ int cur[256];
    const int tid = threadIdx.x;
    const int e0 = blockIdx.x * CHUNK;
    if (tid < 256) cnt[tid] = 0;
    __syncthreads();
    for (int i = tid; i < CHUNK; i += 1024) {
        int e = e0 + i;
        if (e < E) atomicAdd(&cnt[dst[e] >> BSHIFT], 1);
    }
    __syncthreads();
    if (tid < 256) cur[tid] = (cnt[tid] > 0) ? atomicAdd(&gcur[tid], cnt[tid]) : 0;
    __syncthreads();
    for (int i = tid; i < CHUNK; i += 1024) {
        int e = e0 + i;
        if (e < E) {
            int s = src[e], d = dst[e];
            int pos = atomicAdd(&cur[d >> BSHIFT], 1);
            packed[pos] = ((unsigned)(d & (BNODES - 1)) << SRC_BITS) | (unsigned)s;
        }
    }
}

// ---------------- pass 2: per-bucket degree+scan+placement ------------------
// Emits rowptr2 (start,end), dis, and CSR srcs (gapped layout).
__global__ __launch_bounds__(1024) void edge_sort(const unsigned int* __restrict__ packed,
                                                  const int* __restrict__ gcur,
                                                  int2* __restrict__ rowptr2,
                                                  float* __restrict__ dis,
                                                  int* __restrict__ srcs, int n) {
    __shared__ int cnt[BNODES];
    __shared__ int cur[BNODES];
    __shared__ int scn[BNODES];
    const int b = blockIdx.x;
    const int node0 = b << BSHIFT;
    const int tid = threadIdx.x;
    const int base = b * BCAP;
    const int end  = gcur[b];

    if (tid < BNODES) cnt[tid] = 0;
    __syncthreads();
    for (int e = base + tid; e < end; e += 1024)
        atomicAdd(&cnt[packed[e] >> SRC_BITS], 1);
    __syncthreads();
    if (tid < BNODES) scn[tid] = cnt[tid];
    __syncthreads();
    for (int off = 1; off < BNODES; off <<= 1) {
        int t = 0;
        if (tid < BNODES && tid >= off) t = scn[tid - off];
        __syncthreads();
        if (tid < BNODES) scn[tid] += t;
        __syncthreads();
    }
    if (tid < BNODES) {
        int excl = scn[tid] - cnt[tid];
        int node = node0 + tid;
        if (node < n) {
            rowptr2[node] = make_int2(base + excl, base + excl + cnt[tid]);
            dis[node] = rsqrtf((float)cnt[tid] + 1.f);
        }
        cur[tid] = excl;
    }
    __syncthreads();
    for (int e = base + tid; e < end; e += 1024) {
        unsigned p = packed[e];
        int pos = atomicAdd(&cur[p >> SRC_BITS], 1);
        srcs[base + pos] = (int)(p & ((1u << SRC_BITS) - 1));
    }
}

// ---------------- MFMA GEMM: Y[row] = dis[row] * (T(X)[row] @ W) ------------
template<int SRC_F16, int TRANS>
__global__ __launch_bounds__(256) void gemm_mfma(const void* __restrict__ Xv,
                                                 const f16* __restrict__ Wt,
                                                 const float* __restrict__ stats,
                                                 const float* __restrict__ gamma,
                                                 const float* __restrict__ beta,
                                                 const float* __restrict__ dis,
                                                 f16* __restrict__ Y, int n) {
    __shared__ f16 Ah[64][136];
    __shared__ f16 Bh[128][136];
    __shared__ float sc[HC], sh[HC];
    const int tid  = threadIdx.x;
    const int row0 = blockIdx.x * 64;

    if constexpr (TRANS) {
        if (tid < 128) {
            float s = 0.f, q = 0.f;
#pragma unroll
            for (int t = 0; t < NSTRIPE; ++t) {
                s += stats[t * 256 + tid];
                q += stats[t * 256 + 128 + tid];
            }
            float m = s / (float)n;
            float v = q / (float)n - m * m;
            float scv = gamma[tid] * rsqrtf(fmaxf(v, 0.f) + EPS_BN);
            sc[tid] = scv;
            sh[tid] = beta[tid] - m * scv;
        }
    }

#pragma unroll
    for (int i = 0; i < 8; ++i) {
        int idx = i * 256 + tid;
        int r = idx >> 4, g = idx & 15;
        *(f16x8*)&Bh[r][g * 8] = *(const f16x8*)(Wt + (size_t)r * HC + g * 8);
    }
    __syncthreads();

#pragma unroll
    for (int i = 0; i < 4; ++i) {
        int idx = i * 256 + tid;
        int r = idx >> 4, g = idx & 15;
        int grow = row0 + r;
        f16x8 h = {};
        if (grow < n) {
            if constexpr (SRC_F16) {
                f16x8 v = *(const f16x8*)((const f16*)Xv + (size_t)grow * HC + g * 8);
                if constexpr (TRANS) {
#pragma unroll
                    for (int j = 0; j < 8; ++j) {
                        float f = (float)v[j];
                        f = fmaxf(fmaf(f, sc[g * 8 + j], sh[g * 8 + j]), 0.f);
                        h[j] = (f16)f;
                    }
                } else h = v;
            } else {
                const float* X = (const float*)Xv;
                float4 a = *(const float4*)(X + (size_t)grow * HC + g * 8);
                float4 c = *(const float4*)(X + (size_t)grow * HC + g * 8 + 4);
                h[0] = (f16)a.x; h[1] = (f16)a.y; h[2] = (f16)a.z; h[3] = (f16)a.w;
                h[4] = (f16)c.x; h[5] = (f16)c.y; h[6] = (f16)c.z; h[7] = (f16)c.w;
            }
        }
        *(f16x8*)&Ah[r][g * 8] = h;
    }
    __syncthreads();

    const int wv   = tid >> 6;
    const int lane = tid & 63;
    const int m    = lane & 15;
    const int kq   = (lane >> 4) * 8;

    f32x4 acc[8] = {};
#pragma unroll
    for (int kc = 0; kc < HC; kc += 32) {
        f16x8 a = *(const f16x8*)&Ah[wv * 16 + m][kc + kq];
#pragma unroll
        for (int t = 0; t < 8; ++t) {
            f16x8 b = *(const f16x8*)&Bh[t * 16 + m][kc + kq];
            acc[t] = __builtin_amdgcn_mfma_f32_16x16x32_f16(a, b, acc[t], 0, 0, 0);
        }
    }

    const int rbase = row0 + wv * 16 + (lane >> 4) * 4;
#pragma unroll
    for (int r = 0; r < 4; ++r) {
        int grow = rbase + r;
        if (grow < n) {
            float dv = dis[grow];
#pragma unroll
            for (int t = 0; t < 8; ++t)
                Y[(size_t)grow * HC + t * 16 + m] = (f16)(acc[t][r] * dv);
        }
    }
}

// ---------------- CSR gather agg, 8 edges in flight (row-major xws) ---------
// xws[s] = dis[s]*xw[s]; out[v] = dis[v]*(sum_e xws[s] + xws[v]) + b.
__global__ __launch_bounds__(256) void gcn_agg_f16(const f16* __restrict__ xws,
                                                   const int* __restrict__ srcs,
                                                   const int2* __restrict__ rowptr2,
                                                   const float* __restrict__ dis,
                                                   const float* __restrict__ bias,
                                                   f16* __restrict__ out,
                                                   float* __restrict__ stats,
                                                   int n, int nwaves) {
    __shared__ float lds_s[4][128], lds_q[4][128];
    const int wv   = threadIdx.x >> 6;
    const int lane = threadIdx.x & 63;
    const int g    = lane >> 4;      // edge subgroup 0..3
    const int cg   = lane & 15;      // channel group (8 channels)

    float b8[8];
#pragma unroll
    for (int j = 0; j < 8; ++j) b8[j] = bias[cg * 8 + j];

    float s8[8] = {}, q8[8] = {};

    for (int node = blockIdx.x * 4 + wv; node < n; node += nwaves) {
        const int2 rp = rowptr2[node];
        const int e1 = rp.y;
        float acc[8] = {};
        for (int e = rp.x; e < e1; e += 8) {
            int i0 = e + g, i1 = e + g + 4;
            int s0 = (i0 < e1) ? srcs[i0] : n;
            int s1 = (i1 < e1) ? srcs[i1] : n;
            f16x8 v0 = *(const f16x8*)(xws + (size_t)s0 * HC + cg * 8);
            f16x8 v1 = *(const f16x8*)(xws + (size_t)s1 * HC + cg * 8);
#pragma unroll
            for (int j = 0; j < 8; ++j) {
                acc[j] += (float)v0[j];
                acc[j] += (float)v1[j];
            }
        }
#pragma unroll
        for (int j = 0; j < 8; ++j) acc[j] += __shfl_xor(acc[j], 16);
#pragma unroll
        for (int j = 0; j < 8; ++j) acc[j] += __shfl_xor(acc[j], 32);

        if (g == 0) {
            float dv = dis[node];
            f16x8 self = *(const f16x8*)(xws + (size_t)node * HC + cg * 8);
            f16x8 o;
#pragma unroll
            for (int j = 0; j < 8; ++j) {
                float r = fmaf(acc[j] + (float)self[j], dv, b8[j]);
                o[j] = (f16)r;
                s8[j] += r;
                q8[j] += r * r;
            }
            *(f16x8*)(out + (size_t)node * HC + cg * 8) = o;
        }
    }

    if (g == 0) {
#pragma unroll
        for (int j = 0; j < 8; ++j) {
            lds_s[wv][cg * 8 + j] = s8[j];
            lds_q[wv][cg * 8 + j] = q8[j];
        }
    }
    __syncthreads();
    float* stripe = stats + (size_t)(blockIdx.x & (NSTRIPE - 1)) * 256;
    if (threadIdx.x < 128) {
        float s = lds_s[0][threadIdx.x] + lds_s[1][threadIdx.x] +
                  lds_s[2][threadIdx.x] + lds_s[3][threadIdx.x];
        float q = lds_q[0][threadIdx.x] + lds_q[1][threadIdx.x] +
                  lds_q[2][threadIdx.x] + lds_q[3][threadIdx.x];
        atomicAdd(&stripe[threadIdx.x], s);
        atomicAdd(&stripe[128 + threadIdx.x], q);
    }
}

// ---------------- MFMA MLP head (BN2 finalize + BN+ReLU + both layers) ------
__global__ __launch_bounds__(256) void mlp_mfma(const f16* __restrict__ h,
                                                const float* __restrict__ stats,
                                                const float* __restrict__ gamma,
                                                const float* __restrict__ beta,
                                                const f16* __restrict__ Wm1t,
                                                const float* __restrict__ bm1,
                                                const float* __restrict__ Wm2,
                                                const float* __restrict__ bm2,
                                                float* __restrict__ out, int n) {
    __shared__ f16 Hs[64][136];
    __shared__ f16 Ws[64][136];
    __shared__ float sc[HC], sh[HC], bmv[64], w2v[64];
    const int tid  = threadIdx.x;
    const int row0 = blockIdx.x * 64;

    if (tid < 128) {
        float s = 0.f, q = 0.f;
#pragma unroll
        for (int t = 0; t < NSTRIPE; ++t) {
            s += stats[t * 256 + tid];
            q += stats[t * 256 + 128 + tid];
        }
        float m = s / (float)n;
        float v = q / (float)n - m * m;
        float scv = gamma[tid] * rsqrtf(fmaxf(v, 0.f) + EPS_BN);
        sc[tid] = scv;
        sh[tid] = beta[tid] - m * scv;
    }
    if (tid < 64) { bmv[tid] = bm1[tid]; w2v[tid] = Wm2[tid]; }

#pragma unroll
    for (int i = 0; i < 4; ++i) {
        int idx = i * 256 + tid;
        int r = idx >> 4, g = idx & 15;
        *(f16x8*)&Ws[r][g * 8] = *(const f16x8*)(Wm1t + (size_t)r * HC + g * 8);
    }
    __syncthreads();

#pragma unroll
    for (int i = 0; i < 4; ++i) {
        int idx = i * 256 + tid;
        int r = idx >> 4, g = idx & 15;
        int grow = row0 + r;
        f16x8 hv = {};
        if (grow < n) {
            f16x8 v = *(const f16x8*)(h + (size_t)grow * HC + g * 8);
#pragma unroll
            for (int j = 0; j < 8; ++j) {
                float f = (float)v[j];
                f = fmaxf(fmaf(f, sc[g * 8 + j], sh[g * 8 + j]), 0.f);
                hv[j] = (f16)f;
            }
        }
        *(f16x8*)&Hs[r][g * 8] = hv;
    }
    __syncthreads();

    const int wv   = tid >> 6;
    const int lane = tid & 63;
    const int m    = lane & 15;
    const int kq   = (lane >> 4) * 8;

    f32x4 acc[4] = {};
#pragma unroll
    for (int kc = 0; kc < HC; kc += 32) {
        f16x8 a = *(const f16x8*)&Hs[wv * 16 + m][kc + kq];
#pragma unroll
        for (int t = 0; t < 4; ++t) {
            f16x8 b = *(const f16x8*)&Ws[t * 16 + m][kc + kq];
            acc[t] = __builtin_amdgcn_mfma_f32_16x16x32_f16(a, b, acc[t], 0, 0, 0);
        }
    }

    float part[4];
#pragma unroll
    for (int reg = 0; reg < 4; ++reg) {
        float s = 0.f;
#pragma unroll
        for (int t = 0; t < 4; ++t) {
            int col = t * 16 + m;
            s += fmaxf(acc[t][reg] + bmv[col], 0.f) * w2v[col];
        }
        part[reg] = s;
    }
#pragma unroll
    for (int off = 1; off < 16; off <<= 1) {
#pragma unroll
        for (int reg = 0; reg < 4; ++reg)
            part[reg] += __shfl_xor(part[reg], off);
    }
    if (m == 0) {
        int rbase = row0 + wv * 16 + (lane >> 4) * 4;
        float bb = bm2[0];
#pragma unroll
        for (int reg = 0; reg < 4; ++reg) {
            int row = rbase + reg;
            if (row < n) out[row] = part[reg] + bb;
        }
    }
}

extern "C" void kernel_launch(void* const* d_in, const int* in_sizes, int n_in,
                              void* d_out, int out_size, void* d_ws, size_t ws_size,
                              hipStream_t stream) {
    const float* x   = (const float*)d_in[0];
    const int*   ei  = (const int*)  d_in[1];
    const float* W1  = (const float*)d_in[2];
    const float* b1  = (const float*)d_in[3];
    const float* g1  = (const float*)d_in[4];
    const float* be1 = (const float*)d_in[5];
    const float* W2  = (const float*)d_in[6];
    const float* b2  = (const float*)d_in[7];
    const float* g2  = (const float*)d_in[8];
    const float* be2 = (const float*)d_in[9];
    const float* Wm1 = (const float*)d_in[10];
    const float* bm1 = (const float*)d_in[11];
    const float* Wm2 = (const float*)d_in[12];
    const float* bm2 = (const float*)d_in[13];
    float* out = (float*)d_out;

    const int n = in_sizes[0] / HC;       // 100000
    const int E = in_sizes[1] / 2;        // 1600000
    const int* srcp = ei;
    const int* dstp = ei + E;
    const int nb = (n + BNODES - 1) >> BSHIFT;   // 196 buckets

    char* ws = (char*)d_ws;
    size_t off = 0;
    auto alloc = [&](size_t bytes) { void* p = ws + off; off = (off + bytes + 511) & ~511ULL; return p; };
    float*  dis     = (float*) alloc((size_t)n * 4);
    int2*   rowptr2 = (int2*)  alloc((size_t)n * 8);
    int*    gcur    = (int*)   alloc(1024);
    float*  stats   = (float*) alloc(2 * NSTRIPE * 256 * 4);   // stats1 | stats2
    float*  stats1  = stats;
    float*  stats2  = stats + NSTRIPE * 256;
    unsigned int* packed = (unsigned int*)alloc((size_t)nb * BCAP * 4);
    int*    srcs    = (int*)   alloc((size_t)nb * BCAP * 4);
    f16*    xws     = (f16*)   alloc((size_t)(n + 1) * HC * 2);   // +1 zero pad row
    f16*    bufBh   = (f16*)   alloc((size_t)n * HC * 2);
    f16*    Wt1     = (f16*)   alloc((size_t)HC * HC * 2);
    f16*    Wt2     = (f16*)   alloc((size_t)HC * HC * 2);
    f16*    Wm1t    = (f16*)   alloc((size_t)64 * HC * 2);

    const int gemmBlocks = (n + 63) / 64;
    const int binBlocks  = (E + CHUNK - 1) / CHUNK;
    const int aggWaves   = AGG_BLOCKS * 4;

    // ---- prologue: weights + pad row + gcur init + stats zero (1 kernel) ----
    prologue<<<(45440 + 255) / 256, 256, 0, stream>>>(W1, W2, Wm1, Wt1, Wt2, Wm1t,
                                                      xws + (size_t)n * HC, gcur, stats);

    // ---- CSR build: bin into fixed bucket regions -> per-bucket sort ----
    edge_bin<<<binBlocks, 1024, 0, stream>>>(srcp, dstp, gcur, packed, E);
    edge_sort<<<nb, 1024, 0, stream>>>(packed, gcur, rowptr2, dis, srcs, n);

    // ---- layer 1 ----
    gemm_mfma<0, 0><<<gemmBlocks, 256, 0, stream>>>(x, Wt1, nullptr, nullptr, nullptr,
                                                    dis, xws, n);
    gcn_agg_f16<<<AGG_BLOCKS, 256, 0, stream>>>(xws, srcs, rowptr2, dis, b1,
                                                bufBh, stats1, n, aggWaves);

    // ---- layer 2 (BN1 finalize + BN+ReLU fused into GEMM staging) ----
    gemm_mfma<1, 1><<<gemmBlocks, 256, 0, stream>>>(bufBh, Wt2, stats1, g1, be1,
                                                    dis, xws, n);
    gcn_agg_f16<<<AGG_BLOCKS, 256, 0, stream>>>(xws, srcs, rowptr2, dis, b2,
                                                bufBh, stats2, n, aggWaves);

    // ---- MLP head (BN2 finalize + BN+ReLU + both layers fused, MFMA) ----
    mlp_mfma<<<gemmBlocks, 256, 0, stream>>>(bufBh, stats2, g2, be2, Wm1t, bm1, Wm2, bm2,
                                             out, n);
}

// Round 14
// 315.060 us; speedup vs baseline: 1.2985x; 1.0117x over previous
//
#include <hip/hip_runtime.h>
#include <hip/hip_fp16.h>

#define HC 128
#define EPS_BN 1e-5f
#define NSTRIPE 8
#define AGG_BLOCKS 3072
#define BSHIFT 9                 // 512 nodes per bucket
#define BNODES (1 << BSHIFT)
#define BCAP 12288               // bucket capacity (mean 8192 + 45 sigma)
#define CHUNK 8192               // edges per pass-1 block
#define SRC_BITS 18              // src < 2^18

typedef _Float16 f16;
typedef f16  f16x8 __attribute__((ext_vector_type(8)));
typedef float f32x4 __attribute__((ext_vector_type(4)));

// ---------------- tiny init: gcur + stats + pad row (1 block) ---------------
__global__ __launch_bounds__(1024) void init_small(int* __restrict__ gcur,
                                                   float* __restrict__ stats,
                                                   f16* __restrict__ padrow) {
    int tid = threadIdx.x;
    if (tid < 256) gcur[tid] = tid * BCAP;
    if (tid < 128) padrow[tid] = (f16)0.f;
    for (int i = tid; i < 2 * NSTRIPE * 256; i += 1024) stats[i] = 0.f;
}

// ---------------- pass 1: block-private runs into fixed bucket regions ------
// dst cached in registers across the two passes (single HBM read of dst).
__global__ __launch_bounds__(1024) void edge_bin(const int* __restrict__ src,
                                                 const int* __restrict__ dst,
                                                 int* __restrict__ gcur,
                                                 unsigned int* __restrict__ packed, int E) {
    __shared__ int cnt[256];
    __shared__ int cur[256];
    const int tid = threadIdx.x;
    const int e0 = blockIdx.x * CHUNK;
    int dreg[8];
    if (tid < 256) cnt[tid] = 0;
    __syncthreads();
#pragma unroll
    for (int i = 0; i < 8; ++i) {
        int e = e0 + i * 1024 + tid;
        dreg[i] = (e < E) ? dst[e] : -1;
        if (dreg[i] >= 0) atomicAdd(&cnt[dreg[i] >> BSHIFT], 1);
    }
    __syncthreads();
    if (tid < 256) cur[tid] = (cnt[tid] > 0) ? atomicAdd(&gcur[tid], cnt[tid]) : 0;
    __syncthreads();
#pragma unroll
    for (int i = 0; i < 8; ++i) {
        int e = e0 + i * 1024 + tid;
        if (dreg[i] >= 0) {
            int s = src[e];
            int pos = atomicAdd(&cur[dreg[i] >> BSHIFT], 1);
            packed[pos] = ((unsigned)(dreg[i] & (BNODES - 1)) << SRC_BITS) | (unsigned)s;
        }
    }
}

// ---------------- pass 2: per-bucket degree+scan+placement, + wprep blocks --
// Blocks [0,nbSort): bucket sort (rowptr2, dis, srcs).
// Blocks [nbSort,..): weight transposes (consumed later by gemm1/gemm2/mlp).
__global__ __launch_bounds__(1024) void sort_wprep(const unsigned int* __restrict__ packed,
                                                   const int* __restrict__ gcur,
                                                   int2* __restrict__ rowptr2,
                                                   float* __restrict__ dis,
                                                   int* __restrict__ srcs, int n, int nbSort,
                                                   const float* __restrict__ W1,
                                                   const float* __restrict__ W2,
                                                   const float* __restrict__ Wm1,
                                                   f16* __restrict__ Wt1,
                                                   f16* __restrict__ Wt2,
                                                   f16* __restrict__ Wm1t) {
    if (blockIdx.x >= nbSort) {
        int idx = (blockIdx.x - nbSort) * 1024 + threadIdx.x;   // [0, 40960)
        if (idx < 16384) {
            int k = idx >> 7, c = idx & 127;
            Wt1[(size_t)c * HC + k] = (f16)W1[idx];
        } else if (idx < 32768) {
            int i = idx - 16384;
            int k = i >> 7, c = i & 127;
            Wt2[(size_t)c * HC + k] = (f16)W2[i];
        } else if (idx < 40960) {
            int i = idx - 32768;
            int c = i >> 7, k = i & 127;
            Wm1t[(size_t)c * HC + k] = (f16)Wm1[(size_t)k * 64 + c];
        }
        return;
    }
    __shared__ int cnt[BNODES];
    __shared__ int cur[BNODES];
    __shared__ int scn[BNODES];
    const int b = blockIdx.x;
    const int node0 = b << BSHIFT;
    const int tid = threadIdx.x;
    const int base = b * BCAP;
    const int end  = gcur[b];

    if (tid < BNODES) cnt[tid] = 0;
    __syncthreads();
    for (int e = base + tid; e < end; e += 1024)
        atomicAdd(&cnt[packed[e] >> SRC_BITS], 1);
    __syncthreads();
    if (tid < BNODES) scn[tid] = cnt[tid];
    __syncthreads();
    for (int off = 1; off < BNODES; off <<= 1) {
        int t = 0;
        if (tid < BNODES && tid >= off) t = scn[tid - off];
        __syncthreads();
        if (tid < BNODES) scn[tid] += t;
        __syncthreads();
    }
    if (tid < BNODES) {
        int excl = scn[tid] - cnt[tid];
        int node = node0 + tid;
        if (node < n) {
            rowptr2[node] = make_int2(base + excl, base + excl + cnt[tid]);
            dis[node] = rsqrtf((float)cnt[tid] + 1.f);
        }
        cur[tid] = excl;
    }
    __syncthreads();
    for (int e = base + tid; e < end; e += 1024) {
        unsigned p = packed[e];
        int pos = atomicAdd(&cur[p >> SRC_BITS], 1);
        srcs[base + pos] = (int)(p & ((1u << SRC_BITS) - 1));
    }
}

// ---------------- MFMA GEMM: Y[row] = dis[row] * (T(X)[row] @ W) ------------
// Epilogue: LDS transpose (reuse Ah) -> f16x8 vector stores.
template<int SRC_F16, int TRANS>
__global__ __launch_bounds__(256) void gemm_mfma(const void* __restrict__ Xv,
                                                 const f16* __restrict__ Wt,
                                                 const float* __restrict__ stats,
                                                 const float* __restrict__ gamma,
                                                 const float* __restrict__ beta,
                                                 const float* __restrict__ dis,
                                                 f16* __restrict__ Y, int n) {
    __shared__ f16 Ah[64][136];
    __shared__ f16 Bh[128][136];
    __shared__ float sc[HC], sh[HC];
    const int tid  = threadIdx.x;
    const int row0 = blockIdx.x * 64;

    if constexpr (TRANS) {
        if (tid < 128) {
            float s = 0.f, q = 0.f;
#pragma unroll
            for (int t = 0; t < NSTRIPE; ++t) {
                s += stats[t * 256 + tid];
                q += stats[t * 256 + 128 + tid];
            }
            float m = s / (float)n;
            float v = q / (float)n - m * m;
            float scv = gamma[tid] * rsqrtf(fmaxf(v, 0.f) + EPS_BN);
            sc[tid] = scv;
            sh[tid] = beta[tid] - m * scv;
        }
    }

#pragma unroll
    for (int i = 0; i < 8; ++i) {
        int idx = i * 256 + tid;
        int r = idx >> 4, g = idx & 15;
        *(f16x8*)&Bh[r][g * 8] = *(const f16x8*)(Wt + (size_t)r * HC + g * 8);
    }
    __syncthreads();

#pragma unroll
    for (int i = 0; i < 4; ++i) {
        int idx = i * 256 + tid;
        int r = idx >> 4, g = idx & 15;
        int grow = row0 + r;
        f16x8 h = {};
        if (grow < n) {
            if constexpr (SRC_F16) {
                f16x8 v = *(const f16x8*)((const f16*)Xv + (size_t)grow * HC + g * 8);
                if constexpr (TRANS) {
#pragma unroll
                    for (int j = 0; j < 8; ++j) {
                        float f = (float)v[j];
                        f = fmaxf(fmaf(f, sc[g * 8 + j], sh[g * 8 + j]), 0.f);
                        h[j] = (f16)f;
                    }
                } else h = v;
            } else {
                const float* X = (const float*)Xv;
                float4 a = *(const float4*)(X + (size_t)grow * HC + g * 8);
                float4 c = *(const float4*)(X + (size_t)grow * HC + g * 8 + 4);
                h[0] = (f16)a.x; h[1] = (f16)a.y; h[2] = (f16)a.z; h[3] = (f16)a.w;
                h[4] = (f16)c.x; h[5] = (f16)c.y; h[6] = (f16)c.z; h[7] = (f16)c.w;
            }
        }
        *(f16x8*)&Ah[r][g * 8] = h;
    }
    __syncthreads();

    const int wv   = tid >> 6;
    const int lane = tid & 63;
    const int m    = lane & 15;
    const int kq   = (lane >> 4) * 8;

    f32x4 acc[8] = {};
#pragma unroll
    for (int kc = 0; kc < HC; kc += 32) {
        f16x8 a = *(const f16x8*)&Ah[wv * 16 + m][kc + kq];
#pragma unroll
        for (int t = 0; t < 8; ++t) {
            f16x8 b = *(const f16x8*)&Bh[t * 16 + m][kc + kq];
            acc[t] = __builtin_amdgcn_mfma_f32_16x16x32_f16(a, b, acc[t], 0, 0, 0);
        }
    }

    // epilogue: scale by dis, transpose through Ah, vector-store
    __syncthreads();   // all MFMA ds_reads of Ah complete
    {
        const int rg = (lane >> 4) * 4;
        float dv[4];
#pragma unroll
        for (int r = 0; r < 4; ++r) {
            int grow = row0 + wv * 16 + rg + r;
            dv[r] = (grow < n) ? dis[grow] : 0.f;
        }
#pragma unroll
        for (int t = 0; t < 8; ++t)
#pragma unroll
            for (int r = 0; r < 4; ++r)
                Ah[wv * 16 + rg + r][t * 16 + m] = (f16)(acc[t][r] * dv[r]);
    }
    __syncthreads();
#pragma unroll
    for (int i = 0; i < 4; ++i) {
        int idx = i * 256 + tid;
        int r = idx >> 4, g = idx & 15;
        int grow = row0 + r;
        if (grow < n)
            *(f16x8*)(Y + (size_t)grow * HC + g * 8) = *(const f16x8*)&Ah[r][g * 8];
    }
}

// ---------------- CSR gather agg, 8 edges in flight (row-major xws) ---------
// xws[s] = dis[s]*xw[s]; out[v] = dis[v]*(sum_e xws[s] + xws[v]) + b.
__global__ __launch_bounds__(256) void gcn_agg_f16(const f16* __restrict__ xws,
                                                   const int* __restrict__ srcs,
                                                   const int2* __restrict__ rowptr2,
                                                   const float* __restrict__ dis,
                                                   const float* __restrict__ bias,
                                                   f16* __restrict__ out,
                                                   float* __restrict__ stats,
                                                   int n, int nwaves) {
    __shared__ float lds_s[4][128], lds_q[4][128];
    const int wv   = threadIdx.x >> 6;
    const int lane = threadIdx.x & 63;
    const int g    = lane >> 4;      // edge subgroup 0..3
    const int cg   = lane & 15;      // channel group (8 channels)

    float b8[8];
#pragma unroll
    for (int j = 0; j < 8; ++j) b8[j] = bias[cg * 8 + j];

    float s8[8] = {}, q8[8] = {};

    for (int node = blockIdx.x * 4 + wv; node < n; node += nwaves) {
        const int2 rp = rowptr2[node];
        const int e1 = rp.y;
        float acc[8] = {};
        for (int e = rp.x; e < e1; e += 8) {
            int i0 = e + g, i1 = e + g + 4;
            int s0 = (i0 < e1) ? srcs[i0] : n;
            int s1 = (i1 < e1) ? srcs[i1] : n;
            f16x8 v0 = *(const f16x8*)(xws + (size_t)s0 * HC + cg * 8);
            f16x8 v1 = *(const f16x8*)(xws + (size_t)s1 * HC + cg * 8);
#pragma unroll
            for (int j = 0; j < 8; ++j) {
                acc[j] += (float)v0[j];
                acc[j] += (float)v1[j];
            }
        }
#pragma unroll
        for (int j = 0; j < 8; ++j) acc[j] += __shfl_xor(acc[j], 16);
#pragma unroll
        for (int j = 0; j < 8; ++j) acc[j] += __shfl_xor(acc[j], 32);

        if (g == 0) {
            float dv = dis[node];
            f16x8 self = *(const f16x8*)(xws + (size_t)node * HC + cg * 8);
            f16x8 o;
#pragma unroll
            for (int j = 0; j < 8; ++j) {
                float r = fmaf(acc[j] + (float)self[j], dv, b8[j]);
                o[j] = (f16)r;
                s8[j] += r;
                q8[j] += r * r;
            }
            *(f16x8*)(out + (size_t)node * HC + cg * 8) = o;
        }
    }

    if (g == 0) {
#pragma unroll
        for (int j = 0; j < 8; ++j) {
            lds_s[wv][cg * 8 + j] = s8[j];
            lds_q[wv][cg * 8 + j] = q8[j];
        }
    }
    __syncthreads();
    float* stripe = stats + (size_t)(blockIdx.x & (NSTRIPE - 1)) * 256;
    if (threadIdx.x < 128) {
        float s = lds_s[0][threadIdx.x] + lds_s[1][threadIdx.x] +
                  lds_s[2][threadIdx.x] + lds_s[3][threadIdx.x];
        float q = lds_q[0][threadIdx.x] + lds_q[1][threadIdx.x] +
                  lds_q[2][threadIdx.x] + lds_q[3][threadIdx.x];
        atomicAdd(&stripe[threadIdx.x], s);
        atomicAdd(&stripe[128 + threadIdx.x], q);
    }
}

// ---------------- MFMA MLP head (BN2 finalize + BN+ReLU + both layers) ------
__global__ __launch_bounds__(256) void mlp_mfma(const f16* __restrict__ h,
                                                const float* __restrict__ stats,
                                                const float* __restrict__ gamma,
                                                const float* __restrict__ beta,
                                                const f16* __restrict__ Wm1t,
                                                const float* __restrict__ bm1,
                                                const float* __restrict__ Wm2,
                                                const float* __restrict__ bm2,
                                                float* __restrict__ out, int n) {
    __shared__ f16 Hs[64][136];
    __shared__ f16 Ws[64][136];
    __shared__ float sc[HC], sh[HC], bmv[64], w2v[64];
    const int tid  = threadIdx.x;
    const int row0 = blockIdx.x * 64;

    if (tid < 128) {
        float s = 0.f, q = 0.f;
#pragma unroll
        for (int t = 0; t < NSTRIPE; ++t) {
            s += stats[t * 256 + tid];
            q += stats[t * 256 + 128 + tid];
        }
        float m = s / (float)n;
        float v = q / (float)n - m * m;
        float scv = gamma[tid] * rsqrtf(fmaxf(v, 0.f) + EPS_BN);
        sc[tid] = scv;
        sh[tid] = beta[tid] - m * scv;
    }
    if (tid < 64) { bmv[tid] = bm1[tid]; w2v[tid] = Wm2[tid]; }

#pragma unroll
    for (int i = 0; i < 4; ++i) {
        int idx = i * 256 + tid;
        int r = idx >> 4, g = idx & 15;
        *(f16x8*)&Ws[r][g * 8] = *(const f16x8*)(Wm1t + (size_t)r * HC + g * 8);
    }
    __syncthreads();

#pragma unroll
    for (int i = 0; i < 4; ++i) {
        int idx = i * 256 + tid;
        int r = idx >> 4, g = idx & 15;
        int grow = row0 + r;
        f16x8 hv = {};
        if (grow < n) {
            f16x8 v = *(const f16x8*)(h + (size_t)grow * HC + g * 8);
#pragma unroll
            for (int j = 0; j < 8; ++j) {
                float f = (float)v[j];
                f = fmaxf(fmaf(f, sc[g * 8 + j], sh[g * 8 + j]), 0.f);
                hv[j] = (f16)f;
            }
        }
        *(f16x8*)&Hs[r][g * 8] = hv;
    }
    __syncthreads();

    const int wv   = tid >> 6;
    const int lane = tid & 63;
    const int m    = lane & 15;
    const int kq   = (lane >> 4) * 8;

    f32x4 acc[4] = {};
#pragma unroll
    for (int kc = 0; kc < HC; kc += 32) {
        f16x8 a = *(const f16x8*)&Hs[wv * 16 + m][kc + kq];
#pragma unroll
        for (int t = 0; t < 4; ++t) {
            f16x8 b = *(const f16x8*)&Ws[t * 16 + m][kc + kq];
            acc[t] = __builtin_amdgcn_mfma_f32_16x16x32_f16(a, b, acc[t], 0, 0, 0);
        }
    }

    float part[4];
#pragma unroll
    for (int reg = 0; reg < 4; ++reg) {
        float s = 0.f;
#pragma unroll
        for (int t = 0; t < 4; ++t) {
            int col = t * 16 + m;
            s += fmaxf(acc[t][reg] + bmv[col], 0.f) * w2v[col];
        }
        part[reg] = s;
    }
#pragma unroll
    for (int off = 1; off < 16; off <<= 1) {
#pragma unroll
        for (int reg = 0; reg < 4; ++reg)
            part[reg] += __shfl_xor(part[reg], off);
    }
    if (m == 0) {
        int rbase = row0 + wv * 16 + (lane >> 4) * 4;
        float bb = bm2[0];
#pragma unroll
        for (int reg = 0; reg < 4; ++reg) {
            int row = rbase + reg;
            if (row < n) out[row] = part[reg] + bb;
        }
    }
}

extern "C" void kernel_launch(void* const* d_in, const int* in_sizes, int n_in,
                              void* d_out, int out_size, void* d_ws, size_t ws_size,
                              hipStream_t stream) {
    const float* x   = (const float*)d_in[0];
    const int*   ei  = (const int*)  d_in[1];
    const float* W1  = (const float*)d_in[2];
    const float* b1  = (const float*)d_in[3];
    const float* g1  = (const float*)d_in[4];
    const float* be1 = (const float*)d_in[5];
    const float* W2  = (const float*)d_in[6];
    const float* b2  = (const float*)d_in[7];
    const float* g2  = (const float*)d_in[8];
    const float* be2 = (const float*)d_in[9];
    const float* Wm1 = (const float*)d_in[10];
    const float* bm1 = (const float*)d_in[11];
    const float* Wm2 = (const float*)d_in[12];
    const float* bm2 = (const float*)d_in[13];
    float* out = (float*)d_out;

    const int n = in_sizes[0] / HC;       // 100000
    const int E = in_sizes[1] / 2;        // 1600000
    const int* srcp = ei;
    const int* dstp = ei + E;
    const int nb = (n + BNODES - 1) >> BSHIFT;   // 196 buckets

    char* ws = (char*)d_ws;
    size_t off = 0;
    auto alloc = [&](size_t bytes) { void* p = ws + off; off = (off + bytes + 511) & ~511ULL; return p; };
    float*  dis     = (float*) alloc((size_t)n * 4);
    int2*   rowptr2 = (int2*)  alloc((size_t)n * 8);
    int*    gcur    = (int*)   alloc(1024);
    float*  stats   = (float*) alloc(2 * NSTRIPE * 256 * 4);   // stats1 | stats2
    float*  stats1  = stats;
    float*  stats2  = stats + NSTRIPE * 256;
    unsigned int* packed = (unsigned int*)alloc((size_t)nb * BCAP * 4);
    int*    srcs    = (int*)   alloc((size_t)nb * BCAP * 4);
    f16*    xws     = (f16*)   alloc((size_t)(n + 1) * HC * 2);   // +1 zero pad row
    f16*    bufBh   = (f16*)   alloc((size_t)n * HC * 2);
    f16*    Wt1     = (f16*)   alloc((size_t)HC * HC * 2);
    f16*    Wt2     = (f16*)   alloc((size_t)HC * HC * 2);
    f16*    Wm1t    = (f16*)   alloc((size_t)64 * HC * 2);

    const int gemmBlocks = (n + 63) / 64;
    const int binBlocks  = (E + CHUNK - 1) / CHUNK;
    const int wprepBlks  = 40;                    // 40960 / 1024
    const int aggWaves   = AGG_BLOCKS * 4;

    // ---- tiny init (gcur + stats + pad row) ----
    init_small<<<1, 1024, 0, stream>>>(gcur, stats, xws + (size_t)n * HC);

    // ---- CSR build: bin -> per-bucket sort (+ weight prep riding along) ----
    edge_bin<<<binBlocks, 1024, 0, stream>>>(srcp, dstp, gcur, packed, E);
    sort_wprep<<<nb + wprepBlks, 1024, 0, stream>>>(packed, gcur, rowptr2, dis, srcs, n, nb,
                                                    W1, W2, Wm1, Wt1, Wt2, Wm1t);

    // ---- layer 1 ----
    gemm_mfma<0, 0><<<gemmBlocks, 256, 0, stream>>>(x, Wt1, nullptr, nullptr, nullptr,
                                                    dis, xws, n);
    gcn_agg_f16<<<AGG_BLOCKS, 256, 0, stream>>>(xws, srcs, rowptr2, dis, b1,
                                                bufBh, stats1, n, aggWaves);

    // ---- layer 2 (BN1 finalize + BN+ReLU fused into GEMM staging) ----
    gemm_mfma<1, 1><<<gemmBlocks, 256, 0, stream>>>(bufBh, Wt2, stats1, g1, be1,
                                                    dis, xws, n);
    gcn_agg_f16<<<AGG_BLOCKS, 256, 0, stream>>>(xws, srcs, rowptr2, dis, b2,
                                                bufBh, stats2, n, aggWaves);

    // ---- MLP head (BN2 finalize + BN+ReLU + both layers fused, MFMA) ----
    mlp_mfma<<<gemmBlocks, 256, 0, stream>>>(bufBh, stats2, g2, be2, Wm1t, bm1, Wm2, bm2,
                                             out, n);
}

// Round 15
// 310.844 us; speedup vs baseline: 1.3161x; 1.0136x over previous
//
#include <hip/hip_runtime.h>
#include <hip/hip_fp16.h>

#define HC 128
#define EPS_BN 1e-5f
#define NSTRIPE 8
#define AGG_BLOCKS 3072
#define BSHIFT 9                 // 512 nodes per bucket
#define BNODES (1 << BSHIFT)
#define BCAP 12288               // bucket capacity (mean 8192 + 45 sigma)
#define CHUNK 8192               // edges per pass-1 block
#define SRC_BITS 18              // src < 2^18

typedef _Float16 f16;
typedef f16  f16x8 __attribute__((ext_vector_type(8)));
typedef float f32x4 __attribute__((ext_vector_type(4)));

// ---------------- tiny init: gcur + stats + pad row (1 block) ---------------
__global__ __launch_bounds__(1024) void init_small(int* __restrict__ gcur,
                                                   float* __restrict__ stats,
                                                   f16* __restrict__ padrow) {
    int tid = threadIdx.x;
    if (tid < 256) gcur[tid] = tid * BCAP;
    if (tid < 128) padrow[tid] = (f16)0.f;
    for (int i = tid; i < 2 * NSTRIPE * 256; i += 1024) stats[i] = 0.f;
}

// ---------------- pass 1: block-private runs into fixed bucket regions ------
__global__ __launch_bounds__(1024) void edge_bin(const int* __restrict__ src,
                                                 const int* __restrict__ dst,
                                                 int* __restrict__ gcur,
                                                 unsigned int* __restrict__ packed, int E) {
    __shared__ int cnt[256];
    __shared__ int cur[256];
    const int tid = threadIdx.x;
    const int e0 = blockIdx.x * CHUNK;
    int dreg[8];
    if (tid < 256) cnt[tid] = 0;
    __syncthreads();
#pragma unroll
    for (int i = 0; i < 8; ++i) {
        int e = e0 + i * 1024 + tid;
        dreg[i] = (e < E) ? dst[e] : -1;
        if (dreg[i] >= 0) atomicAdd(&cnt[dreg[i] >> BSHIFT], 1);
    }
    __syncthreads();
    if (tid < 256) cur[tid] = (cnt[tid] > 0) ? atomicAdd(&gcur[tid], cnt[tid]) : 0;
    __syncthreads();
#pragma unroll
    for (int i = 0; i < 8; ++i) {
        int e = e0 + i * 1024 + tid;
        if (dreg[i] >= 0) {
            int s = src[e];
            int pos = atomicAdd(&cur[dreg[i] >> BSHIFT], 1);
            packed[pos] = ((unsigned)(dreg[i] & (BNODES - 1)) << SRC_BITS) | (unsigned)s;
        }
    }
}

// ---------------- pass 2: per-bucket degree+scan+placement, + wprep blocks --
__global__ __launch_bounds__(1024) void sort_wprep(const unsigned int* __restrict__ packed,
                                                   const int* __restrict__ gcur,
                                                   int2* __restrict__ rowptr2,
                                                   float* __restrict__ dis,
                                                   int* __restrict__ srcs, int n, int nbSort,
                                                   const float* __restrict__ W1,
                                                   const float* __restrict__ W2,
                                                   const float* __restrict__ Wm1,
                                                   f16* __restrict__ Wt1,
                                                   f16* __restrict__ Wt2,
                                                   f16* __restrict__ Wm1t) {
    if (blockIdx.x >= nbSort) {
        int idx = (blockIdx.x - nbSort) * 1024 + threadIdx.x;   // [0, 40960)
        if (idx < 16384) {
            int k = idx >> 7, c = idx & 127;
            Wt1[(size_t)c * HC + k] = (f16)W1[idx];
        } else if (idx < 32768) {
            int i = idx - 16384;
            int k = i >> 7, c = i & 127;
            Wt2[(size_t)c * HC + k] = (f16)W2[i];
        } else if (idx < 40960) {
            int i = idx - 32768;
            int c = i >> 7, k = i & 127;
            Wm1t[(size_t)c * HC + k] = (f16)Wm1[(size_t)k * 64 + c];
        }
        return;
    }
    __shared__ int cnt[BNODES];
    __shared__ int cur[BNODES];
    __shared__ int scn[BNODES];
    const int b = blockIdx.x;
    const int node0 = b << BSHIFT;
    const int tid = threadIdx.x;
    const int base = b * BCAP;
    const int end  = gcur[b];

    if (tid < BNODES) cnt[tid] = 0;
    __syncthreads();
    for (int e = base + tid; e < end; e += 1024)
        atomicAdd(&cnt[packed[e] >> SRC_BITS], 1);
    __syncthreads();
    if (tid < BNODES) scn[tid] = cnt[tid];
    __syncthreads();
    for (int off = 1; off < BNODES; off <<= 1) {
        int t = 0;
        if (tid < BNODES && tid >= off) t = scn[tid - off];
        __syncthreads();
        if (tid < BNODES) scn[tid] += t;
        __syncthreads();
    }
    if (tid < BNODES) {
        int excl = scn[tid] - cnt[tid];
        int node = node0 + tid;
        if (node < n) {
            rowptr2[node] = make_int2(base + excl, base + excl + cnt[tid]);
            dis[node] = rsqrtf((float)cnt[tid] + 1.f);
        }
        cur[tid] = excl;
    }
    __syncthreads();
    for (int e = base + tid; e < end; e += 1024) {
        unsigned p = packed[e];
        int pos = atomicAdd(&cur[p >> SRC_BITS], 1);
        srcs[base + pos] = (int)(p & ((1u << SRC_BITS) - 1));
    }
}

// ---------------- MFMA GEMM: Y[row] = dis[row] * (T(X)[row] @ W) ------------
// 128 rows / 512 threads per block; B staged once per 128 rows.
template<int SRC_F16, int TRANS>
__global__ __launch_bounds__(512) void gemm_mfma(const void* __restrict__ Xv,
                                                 const f16* __restrict__ Wt,
                                                 const float* __restrict__ stats,
                                                 const float* __restrict__ gamma,
                                                 const float* __restrict__ beta,
                                                 const float* __restrict__ dis,
                                                 f16* __restrict__ Y, int n) {
    __shared__ f16 Ah[128][136];
    __shared__ f16 Bh[128][136];
    __shared__ float sc[HC], sh[HC];
    const int tid  = threadIdx.x;
    const int row0 = blockIdx.x * 128;

    if constexpr (TRANS) {
        if (tid < 128) {
            float s = 0.f, q = 0.f;
#pragma unroll
            for (int t = 0; t < NSTRIPE; ++t) {
                s += stats[t * 256 + tid];
                q += stats[t * 256 + 128 + tid];
            }
            float m = s / (float)n;
            float v = q / (float)n - m * m;
            float scv = gamma[tid] * rsqrtf(fmaxf(v, 0.f) + EPS_BN);
            sc[tid] = scv;
            sh[tid] = beta[tid] - m * scv;
        }
    }

#pragma unroll
    for (int i = 0; i < 4; ++i) {
        int idx = i * 512 + tid;
        int r = idx >> 4, g = idx & 15;
        *(f16x8*)&Bh[r][g * 8] = *(const f16x8*)(Wt + (size_t)r * HC + g * 8);
    }
    __syncthreads();   // sc/sh + Bh visible

#pragma unroll
    for (int i = 0; i < 4; ++i) {
        int idx = i * 512 + tid;
        int r = idx >> 4, g = idx & 15;
        int grow = row0 + r;
        f16x8 h = {};
        if (grow < n) {
            if constexpr (SRC_F16) {
                f16x8 v = *(const f16x8*)((const f16*)Xv + (size_t)grow * HC + g * 8);
                if constexpr (TRANS) {
#pragma unroll
                    for (int j = 0; j < 8; ++j) {
                        float f = (float)v[j];
                        f = fmaxf(fmaf(f, sc[g * 8 + j], sh[g * 8 + j]), 0.f);
                        h[j] = (f16)f;
                    }
                } else h = v;
            } else {
                const float* X = (const float*)Xv;
                float4 a = *(const float4*)(X + (size_t)grow * HC + g * 8);
                float4 c = *(const float4*)(X + (size_t)grow * HC + g * 8 + 4);
                h[0] = (f16)a.x; h[1] = (f16)a.y; h[2] = (f16)a.z; h[3] = (f16)a.w;
                h[4] = (f16)c.x; h[5] = (f16)c.y; h[6] = (f16)c.z; h[7] = (f16)c.w;
            }
        }
        *(f16x8*)&Ah[r][g * 8] = h;
    }
    __syncthreads();

    const int wv   = tid >> 6;          // 0..7, wave handles rows wv*16..+15
    const int lane = tid & 63;
    const int m    = lane & 15;
    const int kq   = (lane >> 4) * 8;

    f32x4 acc[8] = {};
#pragma unroll
    for (int kc = 0; kc < HC; kc += 32) {
        f16x8 a = *(const f16x8*)&Ah[wv * 16 + m][kc + kq];
#pragma unroll
        for (int t = 0; t < 8; ++t) {
            f16x8 b = *(const f16x8*)&Bh[t * 16 + m][kc + kq];
            acc[t] = __builtin_amdgcn_mfma_f32_16x16x32_f16(a, b, acc[t], 0, 0, 0);
        }
    }

    // epilogue: scale by dis, transpose through Ah, vector-store
    __syncthreads();
    {
        const int rg = (lane >> 4) * 4;
        float dv[4];
#pragma unroll
        for (int r = 0; r < 4; ++r) {
            int grow = row0 + wv * 16 + rg + r;
            dv[r] = (grow < n) ? dis[grow] : 0.f;
        }
#pragma unroll
        for (int t = 0; t < 8; ++t)
#pragma unroll
            for (int r = 0; r < 4; ++r)
                Ah[wv * 16 + rg + r][t * 16 + m] = (f16)(acc[t][r] * dv[r]);
    }
    __syncthreads();
#pragma unroll
    for (int i = 0; i < 4; ++i) {
        int idx = i * 512 + tid;
        int r = idx >> 4, g = idx & 15;
        int grow = row0 + r;
        if (grow < n)
            *(f16x8*)(Y + (size_t)grow * HC + g * 8) = *(const f16x8*)&Ah[r][g * 8];
    }
}

// ---------------- CSR gather agg, srcs software-pipelined -------------------
// xws[s] = dis[s]*xw[s]; out[v] = dis[v]*(sum_e xws[s] + xws[v]) + b.
__global__ __launch_bounds__(256) void gcn_agg_f16(const f16* __restrict__ xws,
                                                   const int* __restrict__ srcs,
                                                   const int2* __restrict__ rowptr2,
                                                   const float* __restrict__ dis,
                                                   const float* __restrict__ bias,
                                                   f16* __restrict__ out,
                                                   float* __restrict__ stats,
                                                   int n, int nwaves) {
    __shared__ float lds_s[4][128], lds_q[4][128];
    const int wv   = threadIdx.x >> 6;
    const int lane = threadIdx.x & 63;
    const int g    = lane >> 4;      // edge subgroup 0..3
    const int cg   = lane & 15;      // channel group (8 channels)

    float b8[8];
#pragma unroll
    for (int j = 0; j < 8; ++j) b8[j] = bias[cg * 8 + j];

    float s8[8] = {}, q8[8] = {};

    for (int node = blockIdx.x * 4 + wv; node < n; node += nwaves) {
        const int2 rp = rowptr2[node];
        const int e1 = rp.y;
        float acc[8] = {};
        int e  = rp.x;
        int i0 = e + g, i1 = i0 + 4;
        int s0 = (i0 < e1) ? srcs[i0] : n;
        int s1 = (i1 < e1) ? srcs[i1] : n;
        while (e < e1) {
            int en = e + 8;
            int j0 = en + g, j1 = j0 + 4;
            int t0 = (j0 < e1) ? srcs[j0] : n;     // prefetch next iter's indices
            int t1 = (j1 < e1) ? srcs[j1] : n;
            f16x8 v0 = *(const f16x8*)(xws + (size_t)s0 * HC + cg * 8);
            f16x8 v1 = *(const f16x8*)(xws + (size_t)s1 * HC + cg * 8);
#pragma unroll
            for (int j = 0; j < 8; ++j) {
                acc[j] += (float)v0[j];
                acc[j] += (float)v1[j];
            }
            s0 = t0; s1 = t1; e = en;
        }
#pragma unroll
        for (int j = 0; j < 8; ++j) acc[j] += __shfl_xor(acc[j], 16);
#pragma unroll
        for (int j = 0; j < 8; ++j) acc[j] += __shfl_xor(acc[j], 32);

        if (g == 0) {
            float dv = dis[node];
            f16x8 self = *(const f16x8*)(xws + (size_t)node * HC + cg * 8);
            f16x8 o;
#pragma unroll
            for (int j = 0; j < 8; ++j) {
                float r = fmaf(acc[j] + (float)self[j], dv, b8[j]);
                o[j] = (f16)r;
                s8[j] += r;
                q8[j] += r * r;
            }
            *(f16x8*)(out + (size_t)node * HC + cg * 8) = o;
        }
    }

    if (g == 0) {
#pragma unroll
        for (int j = 0; j < 8; ++j) {
            lds_s[wv][cg * 8 + j] = s8[j];
            lds_q[wv][cg * 8 + j] = q8[j];
        }
    }
    __syncthreads();
    float* stripe = stats + (size_t)(blockIdx.x & (NSTRIPE - 1)) * 256;
    if (threadIdx.x < 128) {
        float s = lds_s[0][threadIdx.x] + lds_s[1][threadIdx.x] +
                  lds_s[2][threadIdx.x] + lds_s[3][threadIdx.x];
        float q = lds_q[0][threadIdx.x] + lds_q[1][threadIdx.x] +
                  lds_q[2][threadIdx.x] + lds_q[3][threadIdx.x];
        atomicAdd(&stripe[threadIdx.x], s);
        atomicAdd(&stripe[128 + threadIdx.x], q);
    }
}

// ---------------- MFMA MLP head (BN2 finalize + BN+ReLU + both layers) ------
__global__ __launch_bounds__(256) void mlp_mfma(const f16* __restrict__ h,
                                                const float* __restrict__ stats,
                                                const float* __restrict__ gamma,
                                                const float* __restrict__ beta,
                                                const f16* __restrict__ Wm1t,
                                                const float* __restrict__ bm1,
                                                const float* __restrict__ Wm2,
                                                const float* __restrict__ bm2,
                                                float* __restrict__ out, int n) {
    __shared__ f16 Hs[64][136];
    __shared__ f16 Ws[64][136];
    __shared__ float sc[HC], sh[HC], bmv[64], w2v[64];
    const int tid  = threadIdx.x;
    const int row0 = blockIdx.x * 64;

    if (tid < 128) {
        float s = 0.f, q = 0.f;
#pragma unroll
        for (int t = 0; t < NSTRIPE; ++t) {
            s += stats[t * 256 + tid];
            q += stats[t * 256 + 128 + tid];
        }
        float m = s / (float)n;
        float v = q / (float)n - m * m;
        float scv = gamma[tid] * rsqrtf(fmaxf(v, 0.f) + EPS_BN);
        sc[tid] = scv;
        sh[tid] = beta[tid] - m * scv;
    }
    if (tid < 64) { bmv[tid] = bm1[tid]; w2v[tid] = Wm2[tid]; }

#pragma unroll
    for (int i = 0; i < 4; ++i) {
        int idx = i * 256 + tid;
        int r = idx >> 4, g = idx & 15;
        *(f16x8*)&Ws[r][g * 8] = *(const f16x8*)(Wm1t + (size_t)r * HC + g * 8);
    }
    __syncthreads();

#pragma unroll
    for (int i = 0; i < 4; ++i) {
        int idx = i * 256 + tid;
        int r = idx >> 4, g = idx & 15;
        int grow = row0 + r;
        f16x8 hv = {};
        if (grow < n) {
            f16x8 v = *(const f16x8*)(h + (size_t)grow * HC + g * 8);
#pragma unroll
            for (int j = 0; j < 8; ++j) {
                float f = (float)v[j];
                f = fmaxf(fmaf(f, sc[g * 8 + j], sh[g * 8 + j]), 0.f);
                hv[j] = (f16)f;
            }
        }
        *(f16x8*)&Hs[r][g * 8] = hv;
    }
    __syncthreads();

    const int wv   = tid >> 6;
    const int lane = tid & 63;
    const int m    = lane & 15;
    const int kq   = (lane >> 4) * 8;

    f32x4 acc[4] = {};
#pragma unroll
    for (int kc = 0; kc < HC; kc += 32) {
        f16x8 a = *(const f16x8*)&Hs[wv * 16 + m][kc + kq];
#pragma unroll
        for (int t = 0; t < 4; ++t) {
            f16x8 b = *(const f16x8*)&Ws[t * 16 + m][kc + kq];
            acc[t] = __builtin_amdgcn_mfma_f32_16x16x32_f16(a, b, acc[t], 0, 0, 0);
        }
    }

    float part[4];
#pragma unroll
    for (int reg = 0; reg < 4; ++reg) {
        float s = 0.f;
#pragma unroll
        for (int t = 0; t < 4; ++t) {
            int col = t * 16 + m;
            s += fmaxf(acc[t][reg] + bmv[col], 0.f) * w2v[col];
        }
        part[reg] = s;
    }
#pragma unroll
    for (int off = 1; off < 16; off <<= 1) {
#pragma unroll
        for (int reg = 0; reg < 4; ++reg)
            part[reg] += __shfl_xor(part[reg], off);
    }
    if (m == 0) {
        int rbase = row0 + wv * 16 + (lane >> 4) * 4;
        float bb = bm2[0];
#pragma unroll
        for (int reg = 0; reg < 4; ++reg) {
            int row = rbase + reg;
            if (row < n) out[row] = part[reg] + bb;
        }
    }
}

extern "C" void kernel_launch(void* const* d_in, const int* in_sizes, int n_in,
                              void* d_out, int out_size, void* d_ws, size_t ws_size,
                              hipStream_t stream) {
    const float* x   = (const float*)d_in[0];
    const int*   ei  = (const int*)  d_in[1];
    const float* W1  = (const float*)d_in[2];
    const float* b1  = (const float*)d_in[3];
    const float* g1  = (const float*)d_in[4];
    const float* be1 = (const float*)d_in[5];
    const float* W2  = (const float*)d_in[6];
    const float* b2  = (const float*)d_in[7];
    const float* g2  = (const float*)d_in[8];
    const float* be2 = (const float*)d_in[9];
    const float* Wm1 = (const float*)d_in[10];
    const float* bm1 = (const float*)d_in[11];
    const float* Wm2 = (const float*)d_in[12];
    const float* bm2 = (const float*)d_in[13];
    float* out = (float*)d_out;

    const int n = in_sizes[0] / HC;       // 100000
    const int E = in_sizes[1] / 2;        // 1600000
    const int* srcp = ei;
    const int* dstp = ei + E;
    const int nb = (n + BNODES - 1) >> BSHIFT;   // 196 buckets

    char* ws = (char*)d_ws;
    size_t off = 0;
    auto alloc = [&](size_t bytes) { void* p = ws + off; off = (off + bytes + 511) & ~511ULL; return p; };
    float*  dis     = (float*) alloc((size_t)n * 4);
    int2*   rowptr2 = (int2*)  alloc((size_t)n * 8);
    int*    gcur    = (int*)   alloc(1024);
    float*  stats   = (float*) alloc(2 * NSTRIPE * 256 * 4);   // stats1 | stats2
    float*  stats1  = stats;
    float*  stats2  = stats + NSTRIPE * 256;
    unsigned int* packed = (unsigned int*)alloc((size_t)nb * BCAP * 4);
    int*    srcs    = (int*)   alloc((size_t)nb * BCAP * 4);
    f16*    xws     = (f16*)   alloc((size_t)(n + 1) * HC * 2);   // +1 zero pad row
    f16*    bufBh   = (f16*)   alloc((size_t)n * HC * 2);
    f16*    Wt1     = (f16*)   alloc((size_t)HC * HC * 2);
    f16*    Wt2     = (f16*)   alloc((size_t)HC * HC * 2);
    f16*    Wm1t    = (f16*)   alloc((size_t)64 * HC * 2);

    const int gemmBlocks = (n + 127) / 128;       // 128-row blocks, 512 threads
    const int mlpBlocks  = (n + 63) / 64;
    const int binBlocks  = (E + CHUNK - 1) / CHUNK;
    const int wprepBlks  = 40;                    // 40960 / 1024
    const int aggWaves   = AGG_BLOCKS * 4;

    // ---- tiny init (gcur + stats + pad row) ----
    init_small<<<1, 1024, 0, stream>>>(gcur, stats, xws + (size_t)n * HC);

    // ---- CSR build: bin -> per-bucket sort (+ weight prep riding along) ----
    edge_bin<<<binBlocks, 1024, 0, stream>>>(srcp, dstp, gcur, packed, E);
    sort_wprep<<<nb + wprepBlks, 1024, 0, stream>>>(packed, gcur, rowptr2, dis, srcs, n, nb,
                                                    W1, W2, Wm1, Wt1, Wt2, Wm1t);

    // ---- layer 1 ----
    gemm_mfma<0, 0><<<gemmBlocks, 512, 0, stream>>>(x, Wt1, nullptr, nullptr, nullptr,
                                                    dis, xws, n);
    gcn_agg_f16<<<AGG_BLOCKS, 256, 0, stream>>>(xws, srcs, rowptr2, dis, b1,
                                                bufBh, stats1, n, aggWaves);

    // ---- layer 2 (BN1 finalize + BN+ReLU fused into GEMM staging) ----
    gemm_mfma<1, 1><<<gemmBlocks, 512, 0, stream>>>(bufBh, Wt2, stats1, g1, be1,
                                                    dis, xws, n);
    gcn_agg_f16<<<AGG_BLOCKS, 256, 0, stream>>>(xws, srcs, rowptr2, dis, b2,
                                                bufBh, stats2, n, aggWaves);

    // ---- MLP head (BN2 finalize + BN+ReLU + both layers fused, MFMA) ----
    mlp_mfma<<<mlpBlocks, 256, 0, stream>>>(bufBh, stats2, g2, be2, Wm1t, bm1, Wm2, bm2,
                                            out, n);
}